// Round 1
// baseline (445.143 us; speedup 1.0000x reference)
//
#include <hip/hip_runtime.h>
#include <hip/hip_bf16.h>

#define T_SEQ 2048
#define NHEAD 16
#define HDIM  64
#define CDIM  1024

typedef __attribute__((ext_vector_type(8))) short bf16x8;
typedef __attribute__((ext_vector_type(4))) float f32x4;

__device__ __forceinline__ unsigned short f2bf(float f) {
  union { __hip_bfloat16 h; unsigned short u; } c;
  c.h = __float2bfloat16(f);
  return c.u;
}

#define GLD16(g, l) __builtin_amdgcn_global_load_lds( \
  (const __attribute__((address_space(1))) void*)(g), \
  (__attribute__((address_space(3))) void*)(l), 16, 0, 0)

// ---------------- elementwise f32 -> bf16 cast (vectorized) ----------------
__global__ void cvt_bf16(const float* __restrict__ in, unsigned short* __restrict__ out, int n4) {
  const int i = blockIdx.x * 256 + threadIdx.x;
  if (i >= n4) return;
  const float4 v = ((const float4*)in)[i];
  ushort4 o;
  o.x = f2bf(v.x); o.y = f2bf(v.y); o.z = f2bf(v.z); o.w = f2bf(v.w);
  ((ushort4*)out)[i] = o;
}

// ---------------- tiled transpose f32[R][C] -> bf16[C][R] ----------------
__global__ void transpose_cvt(const float* __restrict__ in, unsigned short* __restrict__ out,
                              int R, int C) {
  __shared__ float tile[32][33];
  const int tx = threadIdx.x & 31, ty = threadIdx.x >> 5;
  const int c0 = blockIdx.x * 32, r0 = blockIdx.y * 32;
#pragma unroll
  for (int i = 0; i < 32; i += 8)
    tile[ty + i][tx] = in[(size_t)(r0 + ty + i) * C + c0 + tx];
  __syncthreads();
#pragma unroll
  for (int i = 0; i < 32; i += 8)
    out[(size_t)(c0 + ty + i) * R + r0 + tx] = f2bf(tile[tx][ty + i]);
}

// ---------------- bf16 MFMA GEMM: C[M][N] = A[M][K] * BT[N][K]^T + bias ----------------
// 128x128 tile, BK=32, 4 waves (2x2), each wave 64x64 = 4x4 fragments of 16x16x32.
template<int OUTF32>
__global__ __launch_bounds__(256, 2)
void gemm_bt(const unsigned short* __restrict__ A, const unsigned short* __restrict__ BT,
             const float* __restrict__ bias, void* __restrict__ outp,
             int M, int N, int K) {
  const int tid = threadIdx.x;
  const int w = tid >> 6, lane = tid & 63;
  const int lg = lane >> 4, l15 = lane & 15;
  const int wr = w >> 1, wc = w & 1;
  const int n0 = blockIdx.x * 128, m0 = blockIdx.y * 128;

  __shared__ unsigned short As[128 * 32];
  __shared__ unsigned short Bs[128 * 32];

  f32x4 acc[4][4] = {};

  for (int k0 = 0; k0 < K; k0 += 32) {
    __syncthreads();
#pragma unroll
    for (int i = 0; i < 2; ++i) {
      const int cb = i * 256 + w * 64;   // wave-uniform chunk base
      const int c  = cb + lane;          // per-lane chunk
      const int row = c >> 2, slot = c & 3;
      GLD16(A  + (size_t)(m0 + row) * K + k0 + slot * 8, (char*)As + cb * 16);
      GLD16(BT + (size_t)(n0 + row) * K + k0 + slot * 8, (char*)Bs + cb * 16);
    }
    __syncthreads();
    bf16x8 af[4], bfr[4];
#pragma unroll
    for (int mt = 0; mt < 4; ++mt)
      af[mt] = *(const bf16x8*)&As[(wr * 64 + mt * 16 + l15) * 32 + lg * 8];
#pragma unroll
    for (int nt = 0; nt < 4; ++nt)
      bfr[nt] = *(const bf16x8*)&Bs[(wc * 64 + nt * 16 + l15) * 32 + lg * 8];
#pragma unroll
    for (int mt = 0; mt < 4; ++mt)
#pragma unroll
      for (int nt = 0; nt < 4; ++nt)
        acc[mt][nt] = __builtin_amdgcn_mfma_f32_16x16x32_bf16(af[mt], bfr[nt], acc[mt][nt], 0, 0, 0);
  }

#pragma unroll
  for (int mt = 0; mt < 4; ++mt) {
#pragma unroll
    for (int nt = 0; nt < 4; ++nt) {
      const int col = n0 + wc * 64 + nt * 16 + l15;
      const float bv = bias[col];
#pragma unroll
      for (int j = 0; j < 4; ++j) {
        const int row = m0 + wr * 64 + mt * 16 + lg * 4 + j;
        const float v = acc[mt][nt][j] + bv;
        if (OUTF32) ((float*)outp)[(size_t)row * N + col] = v;
        else ((unsigned short*)outp)[(size_t)row * N + col] = f2bf(v);
      }
    }
  }
}

// ---------------- causal flash attention ----------------
// qkv: bf16 [B*T][3C], layout q|k|v each [C], head h at offset h*64.
// Block: 256 threads = 4 waves; block covers 128 Q rows of one (b,h); wave w owns 32 rows.
// KV tiles of 32. att out: bf16 [B*T][C].
__global__ __launch_bounds__(256, 2)
void attn_causal(const unsigned short* __restrict__ qkv, unsigned short* __restrict__ att) {
  const int tid = threadIdx.x;
  const int w = tid >> 6, lane = tid & 63;
  const int lg = lane >> 4, l15 = lane & 15;
  const int bh = blockIdx.y;
  const int b = bh >> 4, h = bh & 15;
  const int q0 = blockIdx.x * 128;

  __shared__ unsigned short Kl[32 * 64];      // K tile [kv][d]
  __shared__ unsigned short Vt[64 * 32];      // V tile transposed [d][kv]
  __shared__ unsigned short Pl[4][32 * 32];   // per-wave P [q][kv]

  const unsigned short* base = qkv + (size_t)b * T_SEQ * 3072;

  // load Q fragments (held in regs the whole kernel)
  bf16x8 qf[2][2];
  const int qw = q0 + w * 32;
#pragma unroll
  for (int rt = 0; rt < 2; ++rt)
#pragma unroll
    for (int kc = 0; kc < 2; ++kc)
      qf[rt][kc] = *(const bf16x8*)(base + (size_t)(qw + rt * 16 + l15) * 3072 + h * 64 + kc * 32 + lg * 8);

  f32x4 oacc[2][4] = {};
  float mst[2][4], lst[2][4];
#pragma unroll
  for (int rt = 0; rt < 2; ++rt)
#pragma unroll
    for (int j = 0; j < 4; ++j) { mst[rt][j] = -1e30f; lst[rt][j] = 0.f; }

  const int ntiles = (q0 + 128) >> 5;
  for (int t = 0; t < ntiles; ++t) {
    const int kv0 = t << 5;
    __syncthreads();   // protect LDS reuse from previous iteration
    {   // stage K tile [32][64] via global_load_lds: 256 chunks of 16B, one per thread
      const int row = tid >> 3, slot = tid & 7;
      GLD16(base + (size_t)(kv0 + row) * 3072 + 1024 + h * 64 + slot * 8,
            (char*)Kl + w * 1024);
    }
    {   // stage V transposed via registers
      const int kv = tid & 31, d0 = (tid >> 5) * 8;
      bf16x8 v8 = *(const bf16x8*)(base + (size_t)(kv0 + kv) * 3072 + 2048 + h * 64 + d0);
#pragma unroll
      for (int j = 0; j < 8; ++j)
        Vt[(d0 + j) * 32 + kv] = (unsigned short)v8[j];
    }
    __syncthreads();

    // S = Q K^T, softmax, write P
#pragma unroll
    for (int rt = 0; rt < 2; ++rt) {
      f32x4 sc0 = {}, sc1 = {};
#pragma unroll
      for (int kc = 0; kc < 2; ++kc) {
        bf16x8 kf0 = *(const bf16x8*)&Kl[(l15) * 64 + kc * 32 + lg * 8];
        bf16x8 kf1 = *(const bf16x8*)&Kl[(16 + l15) * 64 + kc * 32 + lg * 8];
        sc0 = __builtin_amdgcn_mfma_f32_16x16x32_bf16(qf[rt][kc], kf0, sc0, 0, 0, 0);
        sc1 = __builtin_amdgcn_mfma_f32_16x16x32_bf16(qf[rt][kc], kf1, sc1, 0, 0, 0);
      }
      const int qg = q0 + w * 32 + rt * 16 + lg * 4;
      const int kg0 = kv0 + l15, kg1 = kv0 + 16 + l15;
      float s0[4], s1[4], mx[4];
#pragma unroll
      for (int j = 0; j < 4; ++j) {
        s0[j] = (kg0 <= qg + j) ? sc0[j] * 0.125f : -1e30f;
        s1[j] = (kg1 <= qg + j) ? sc1[j] * 0.125f : -1e30f;
        mx[j] = fmaxf(s0[j], s1[j]);
      }
#pragma unroll
      for (int o = 1; o < 16; o <<= 1)
#pragma unroll
        for (int j = 0; j < 4; ++j)
          mx[j] = fmaxf(mx[j], __shfl_xor(mx[j], o));
      float p0[4], p1[4], rs[4];
#pragma unroll
      for (int j = 0; j < 4; ++j) {
        const float mnew = fmaxf(mst[rt][j], mx[j]);
        const float al = __expf(mst[rt][j] - mnew);
        mst[rt][j] = mnew;
        p0[j] = __expf(s0[j] - mnew);
        p1[j] = __expf(s1[j] - mnew);
        rs[j] = p0[j] + p1[j];
        lst[rt][j] *= al;
#pragma unroll
        for (int dt = 0; dt < 4; ++dt) oacc[rt][dt][j] *= al;
      }
#pragma unroll
      for (int o = 1; o < 16; o <<= 1)
#pragma unroll
        for (int j = 0; j < 4; ++j)
          rs[j] += __shfl_xor(rs[j], o);
#pragma unroll
      for (int j = 0; j < 4; ++j) lst[rt][j] += rs[j];
#pragma unroll
      for (int j = 0; j < 4; ++j) {
        const int pr = rt * 16 + lg * 4 + j;
        Pl[w][pr * 32 + l15]      = f2bf(p0[j]);
        Pl[w][pr * 32 + 16 + l15] = f2bf(p1[j]);
      }
    }
    __syncthreads();

    // O += P V
    bf16x8 vb[4];
#pragma unroll
    for (int dt = 0; dt < 4; ++dt)
      vb[dt] = *(const bf16x8*)&Vt[(dt * 16 + l15) * 32 + lg * 8];
#pragma unroll
    for (int rt = 0; rt < 2; ++rt) {
      bf16x8 pa = *(const bf16x8*)&Pl[w][(rt * 16 + l15) * 32 + lg * 8];
#pragma unroll
      for (int dt = 0; dt < 4; ++dt)
        oacc[rt][dt] = __builtin_amdgcn_mfma_f32_16x16x32_bf16(pa, vb[dt], oacc[rt][dt], 0, 0, 0);
    }
  }

  // epilogue: normalize, write att [B*T][C] bf16
#pragma unroll
  for (int rt = 0; rt < 2; ++rt) {
#pragma unroll
    for (int dt = 0; dt < 4; ++dt) {
#pragma unroll
      for (int j = 0; j < 4; ++j) {
        const int q = q0 + w * 32 + rt * 16 + lg * 4 + j;
        const float v = oacc[rt][dt][j] / lst[rt][j];
        att[(size_t)(b * T_SEQ + q) * CDIM + h * HDIM + dt * 16 + l15] = f2bf(v);
      }
    }
  }
}

// ---------------- launcher ----------------
extern "C" void kernel_launch(void* const* d_in, const int* in_sizes, int n_in,
                              void* d_out, int out_size, void* d_ws, size_t ws_size,
                              hipStream_t stream) {
  const float* x      = (const float*)d_in[0];
  const float* w_attn = (const float*)d_in[1];
  const float* b_attn = (const float*)d_in[2];
  const float* w_proj = (const float*)d_in[3];
  const float* b_proj = (const float*)d_in[4];
  float* out = (float*)d_out;

  char* ws = (char*)d_ws;
  unsigned short* xb  = (unsigned short*)(ws + 0);           // 8192*1024 bf16
  unsigned short* wat = (unsigned short*)(ws + 16777216);    // 3072*1024 bf16 (w_attn^T)
  unsigned short* wpt = (unsigned short*)(ws + 23068672);    // 1024*1024 bf16 (w_proj^T)
  unsigned short* qkv = (unsigned short*)(ws + 25165824);    // 8192*3072 bf16
  unsigned short* att = (unsigned short*)(ws + 75497472);    // 8192*1024 bf16

  // 1. cast x to bf16
  cvt_bf16<<<8192, 256, 0, stream>>>(x, xb, 2097152);
  // 2. transpose+cast weights
  transpose_cvt<<<dim3(96, 32), 256, 0, stream>>>(w_attn, wat, 1024, 3072);
  transpose_cvt<<<dim3(32, 32), 256, 0, stream>>>(w_proj, wpt, 1024, 1024);
  // 3. QKV GEMM -> qkv bf16 [8192][3072]
  gemm_bt<0><<<dim3(24, 64), 256, 0, stream>>>(xb, wat, b_attn, (void*)qkv, 8192, 3072, 1024);
  // 4. causal flash attention -> att bf16 [8192][1024]
  attn_causal<<<dim3(16, 64), 256, 0, stream>>>(qkv, att);
  // 5. projection GEMM -> out f32
  gemm_bt<1><<<dim3(8, 64), 256, 0, stream>>>(att, wpt, b_proj, d_out, 8192, 1024, 1024);
}

// Round 2
// 239.083 us; speedup vs baseline: 1.8619x; 1.8619x over previous
//
#include <hip/hip_runtime.h>
#include <hip/hip_bf16.h>

#define T_SEQ 2048
#define NHEAD 16
#define HDIM  64
#define CDIM  1024

typedef __attribute__((ext_vector_type(8))) short bf16x8;
typedef __attribute__((ext_vector_type(4))) float f32x4;

__device__ __forceinline__ unsigned short f2bf(float f) {
  union { __hip_bfloat16 h; unsigned short u; } c;
  c.h = __float2bfloat16(f);
  return c.u;
}

#define GLD16(g, l) __builtin_amdgcn_global_load_lds( \
  (const __attribute__((address_space(1))) void*)(g), \
  (__attribute__((address_space(3))) void*)(l), 16, 0, 0)

// ---------------- elementwise f32 -> bf16 cast (vectorized) ----------------
__global__ void cvt_bf16(const float* __restrict__ in, unsigned short* __restrict__ out, int n4) {
  const int i = blockIdx.x * 256 + threadIdx.x;
  if (i >= n4) return;
  const float4 v = ((const float4*)in)[i];
  ushort4 o;
  o.x = f2bf(v.x); o.y = f2bf(v.y); o.z = f2bf(v.z); o.w = f2bf(v.w);
  ((ushort4*)out)[i] = o;
}

// ---------------- tiled transpose f32[R][C] -> bf16[C][R] ----------------
__global__ void transpose_cvt(const float* __restrict__ in, unsigned short* __restrict__ out,
                              int R, int C) {
  __shared__ float tile[32][33];
  const int tx = threadIdx.x & 31, ty = threadIdx.x >> 5;
  const int c0 = blockIdx.x * 32, r0 = blockIdx.y * 32;
#pragma unroll
  for (int i = 0; i < 32; i += 8)
    tile[ty + i][tx] = in[(size_t)(r0 + ty + i) * C + c0 + tx];
  __syncthreads();
#pragma unroll
  for (int i = 0; i < 32; i += 8)
    out[(size_t)(c0 + ty + i) * R + r0 + tx] = f2bf(tile[tx][ty + i]);
}

// ---------------- bf16 MFMA GEMM: C[M][N] = A[M][K] * BT[N][K]^T + bias ----------------
// 128x128 tile, BK=32, 4 waves (2x2), each wave 64x64 = 4x4 fragments of 16x16x32.
template<int OUTF32>
__global__ __launch_bounds__(256, 2)
void gemm_bt(const unsigned short* __restrict__ A, const unsigned short* __restrict__ BT,
             const float* __restrict__ bias, void* __restrict__ outp,
             int M, int N, int K) {
  const int tid = threadIdx.x;
  const int w = tid >> 6, lane = tid & 63;
  const int lg = lane >> 4, l15 = lane & 15;
  const int wr = w >> 1, wc = w & 1;
  const int n0 = blockIdx.x * 128, m0 = blockIdx.y * 128;

  __shared__ unsigned short As[128 * 32];
  __shared__ unsigned short Bs[128 * 32];

  f32x4 acc[4][4] = {};

  for (int k0 = 0; k0 < K; k0 += 32) {
    __syncthreads();
#pragma unroll
    for (int i = 0; i < 2; ++i) {
      const int cb = i * 256 + w * 64;   // wave-uniform chunk base
      const int c  = cb + lane;          // per-lane chunk
      const int row = c >> 2, slot = c & 3;
      GLD16(A  + (size_t)(m0 + row) * K + k0 + slot * 8, (char*)As + cb * 16);
      GLD16(BT + (size_t)(n0 + row) * K + k0 + slot * 8, (char*)Bs + cb * 16);
    }
    __syncthreads();
    bf16x8 af[4], bfr[4];
#pragma unroll
    for (int mt = 0; mt < 4; ++mt)
      af[mt] = *(const bf16x8*)&As[(wr * 64 + mt * 16 + l15) * 32 + lg * 8];
#pragma unroll
    for (int nt = 0; nt < 4; ++nt)
      bfr[nt] = *(const bf16x8*)&Bs[(wc * 64 + nt * 16 + l15) * 32 + lg * 8];
#pragma unroll
    for (int mt = 0; mt < 4; ++mt)
#pragma unroll
      for (int nt = 0; nt < 4; ++nt)
        acc[mt][nt] = __builtin_amdgcn_mfma_f32_16x16x32_bf16(af[mt], bfr[nt], acc[mt][nt], 0, 0, 0);
  }

#pragma unroll
  for (int mt = 0; mt < 4; ++mt) {
#pragma unroll
    for (int nt = 0; nt < 4; ++nt) {
      const int col = n0 + wc * 64 + nt * 16 + l15;
      const float bv = bias[col];
#pragma unroll
      for (int j = 0; j < 4; ++j) {
        const int row = m0 + wr * 64 + mt * 16 + lg * 4 + j;
        const float v = acc[mt][nt][j] + bv;
        if (OUTF32) ((float*)outp)[(size_t)row * N + col] = v;
        else ((unsigned short*)outp)[(size_t)row * N + col] = f2bf(v);
      }
    }
  }
}

// ---------------- causal flash attention v2 ----------------
// qkv bf16 [B*T][3C]. Block = 256 threads (4 waves), each wave owns 16 q rows.
// Block processes TWO q-tiles {pair, 31-pair} of 64 rows -> uniform 33 KV-tiles/block.
// KVBLK=64, double-buffered K/V, ONE barrier per tile, prefetch overlapped.
__global__ __launch_bounds__(256, 4)
void attn_causal2(const unsigned short* __restrict__ qkv, unsigned short* __restrict__ att) {
  const int tid = threadIdx.x;
  const int w = tid >> 6, lane = tid & 63;
  const int lg = lane >> 4, l15 = lane & 15;

  // XCD-chunked remap: launched fid runs on XCD fid%8 (round-robin assumption);
  // give each XCD a contiguous chunk of 128 work items = 8 (b,h) pairs (4MB KV = one L2).
  const int fid = blockIdx.x + (blockIdx.y << 4);      // grid (16,64)
  const int f2 = (fid & 7) * 128 + (fid >> 3);
  const int pair = f2 & 15, bh = f2 >> 4;
  const int b = bh >> 4, h = bh & 15;

  __shared__ unsigned short Kl[2][2][64][32];   // [buf][kc-half][kv][kel] 64B rows (b128 floor)
  __shared__ unsigned short Vt[2][2][64][32];   // [buf][ks-half][d][kv]  slot-XOR swizzled
  __shared__ unsigned short Pl[4][2][16][32];   // [wave][ks-half][q][kv] slot-XOR swizzled

  const unsigned short* base = qkv + (size_t)b * T_SEQ * 3072;

  // K stage: tile = [2 kc][64 kv][32 el] linear = 512 x 16B chunks, gld_lds direct.
  auto STAGE_K = [&](int kv0, int buf) {
#pragma unroll
    for (int i = 0; i < 2; ++i) {
      const int cb = w * 128 + i * 64;
      const int c = cb + lane;
      const int kc = c >> 8, row = (c >> 2) & 63, s2 = c & 3;
      GLD16(base + (size_t)(kv0 + row) * 3072 + 1024 + h * 64 + kc * 32 + s2 * 8,
            (char*)&Kl[buf][0][0][0] + cb * 16);
    }
  };

  bf16x8 vr[2];
  auto VLOAD = [&](int kv0) {
#pragma unroll
    for (int i = 0; i < 2; ++i) {
      const int c = tid + i * 256;
      const int row = c >> 3, ds = c & 7;
      vr[i] = *(const bf16x8*)(base + (size_t)(kv0 + row) * 3072 + 2048 + h * 64 + ds * 8);
    }
  };
  auto VWRITE = [&](int buf) {
#pragma unroll
    for (int i = 0; i < 2; ++i) {
      const int c = tid + i * 256;
      const int row = c >> 3, ds = c & 7;
      const int ks = row >> 5, kvl = row & 31;
      const int pos = (kvl & 7) + 8 * ((kvl >> 3) ^ (ds & 3));   // XOR by (d>>3)&3
#pragma unroll
      for (int j = 0; j < 8; ++j)
        Vt[buf][ks][ds * 8 + j][pos] = (unsigned short)vr[i][j];
    }
  };

  for (int half = 0; half < 2; ++half) {
    const int qt = half ? (31 - pair) : pair;
    const int q0 = qt << 6;
    const int nt = qt + 1;
    const int rbase = q0 + w * 16 + lg * 4;

    // Q fragments in regs
    bf16x8 qf[2];
    {
      const int qrow = q0 + w * 16 + l15;
#pragma unroll
      for (int kc = 0; kc < 2; ++kc)
        qf[kc] = *(const bf16x8*)(base + (size_t)qrow * 3072 + h * 64 + kc * 32 + lg * 8);
    }

    f32x4 oacc[4] = {};
    float mst[4], lst[4];
#pragma unroll
    for (int j = 0; j < 4; ++j) { mst[j] = -1e30f; lst[j] = 0.f; }

    // prologue: stage tile 0 into buf 0
    STAGE_K(0, 0);
    VLOAD(0);
    VWRITE(0);
    __syncthreads();

    for (int t = 0; t < nt; ++t) {
      const int cur = t & 1, nxt = cur ^ 1;
      const bool pf = (t + 1) < nt;
      if (pf) { STAGE_K((t + 1) << 6, nxt); VLOAD((t + 1) << 6); }
      const int kv0 = t << 6;

      // ---- QK^T ----
      f32x4 sc[4];
#pragma unroll
      for (int kg = 0; kg < 4; ++kg) {
        f32x4 s = {};
#pragma unroll
        for (int kc = 0; kc < 2; ++kc) {
          bf16x8 kf = *(const bf16x8*)&Kl[cur][kc][kg * 16 + l15][lg * 8];
          s = __builtin_amdgcn_mfma_f32_16x16x32_bf16(qf[kc], kf, s, 0, 0, 0);
        }
        sc[kg] = s;
      }

      // ---- mask + online softmax ----
      float sv[4][4], mx[4];
#pragma unroll
      for (int j = 0; j < 4; ++j) mx[j] = -1e30f;
#pragma unroll
      for (int kg = 0; kg < 4; ++kg) {
        const int col = kv0 + kg * 16 + l15;
#pragma unroll
        for (int j = 0; j < 4; ++j) {
          const float s = (col <= rbase + j) ? sc[kg][j] * 0.125f : -1e30f;
          sv[kg][j] = s;
          mx[j] = fmaxf(mx[j], s);
        }
      }
#pragma unroll
      for (int o = 1; o < 16; o <<= 1)
#pragma unroll
        for (int j = 0; j < 4; ++j)
          mx[j] = fmaxf(mx[j], __shfl_xor(mx[j], o));

      float al[4], rs[4];
#pragma unroll
      for (int j = 0; j < 4; ++j) {
        const float mnew = fmaxf(mst[j], mx[j]);
        al[j] = __expf(mst[j] - mnew);
        mst[j] = mnew;
        rs[j] = 0.f;
      }
#pragma unroll
      for (int kg = 0; kg < 4; ++kg) {
        const int pos = (l15 & 7) + 8 * ((((kg & 1) << 1) + (l15 >> 3)) ^ lg);
#pragma unroll
        for (int j = 0; j < 4; ++j) {
          const float p = __expf(sv[kg][j] - mst[j]);
          rs[j] += p;
          Pl[w][kg >> 1][lg * 4 + j][pos] = f2bf(p);
        }
      }
#pragma unroll
      for (int o = 1; o < 16; o <<= 1)
#pragma unroll
        for (int j = 0; j < 4; ++j)
          rs[j] += __shfl_xor(rs[j], o);
#pragma unroll
      for (int j = 0; j < 4; ++j) {
        lst[j] = lst[j] * al[j] + rs[j];
#pragma unroll
        for (int dt = 0; dt < 4; ++dt) oacc[dt][j] *= al[j];
      }

      // P writes are cross-lane within this wave only: drain LDS, fence scheduler
      asm volatile("s_waitcnt lgkmcnt(0)" ::: "memory");
      __builtin_amdgcn_sched_barrier(0);

      // ---- PV ----
      bf16x8 pa[2];
#pragma unroll
      for (int ks = 0; ks < 2; ++ks)
        pa[ks] = *(const bf16x8*)&Pl[w][ks][l15][(lg ^ ((l15 >> 2) & 3)) * 8];
#pragma unroll
      for (int dt = 0; dt < 4; ++dt) {
        f32x4 o = oacc[dt];
#pragma unroll
        for (int ks = 0; ks < 2; ++ks) {
          const int r = dt * 16 + l15;
          bf16x8 vb = *(const bf16x8*)&Vt[cur][ks][r][(lg ^ ((r >> 3) & 3)) * 8];
          o = __builtin_amdgcn_mfma_f32_16x16x32_bf16(pa[ks], vb, o, 0, 0, 0);
        }
        oacc[dt] = o;
      }

      if (pf) VWRITE(nxt);
      __syncthreads();   // drains vmcnt (K gld_lds) + lgkm (V writes); buffers swap
    }

    // ---- epilogue ----
#pragma unroll
    for (int dt = 0; dt < 4; ++dt) {
#pragma unroll
      for (int j = 0; j < 4; ++j) {
        const int q = rbase + j;
        att[(size_t)(b * T_SEQ + q) * CDIM + h * HDIM + dt * 16 + l15] =
            f2bf(oacc[dt][j] / lst[j]);
      }
    }
  }
}

// ---------------- launcher ----------------
extern "C" void kernel_launch(void* const* d_in, const int* in_sizes, int n_in,
                              void* d_out, int out_size, void* d_ws, size_t ws_size,
                              hipStream_t stream) {
  const float* x      = (const float*)d_in[0];
  const float* w_attn = (const float*)d_in[1];
  const float* b_attn = (const float*)d_in[2];
  const float* w_proj = (const float*)d_in[3];
  const float* b_proj = (const float*)d_in[4];

  char* ws = (char*)d_ws;
  unsigned short* xb  = (unsigned short*)(ws + 0);           // 8192*1024 bf16
  unsigned short* wat = (unsigned short*)(ws + 16777216);    // 3072*1024 bf16 (w_attn^T)
  unsigned short* wpt = (unsigned short*)(ws + 23068672);    // 1024*1024 bf16 (w_proj^T)
  unsigned short* qkv = (unsigned short*)(ws + 25165824);    // 8192*3072 bf16
  unsigned short* att = (unsigned short*)(ws + 75497472);    // 8192*1024 bf16

  cvt_bf16<<<8192, 256, 0, stream>>>(x, xb, 2097152);
  transpose_cvt<<<dim3(96, 32), 256, 0, stream>>>(w_attn, wat, 1024, 3072);
  transpose_cvt<<<dim3(32, 32), 256, 0, stream>>>(w_proj, wpt, 1024, 1024);
  gemm_bt<0><<<dim3(24, 64), 256, 0, stream>>>(xb, wat, b_attn, (void*)qkv, 8192, 3072, 1024);
  attn_causal2<<<dim3(16, 64), 256, 0, stream>>>(qkv, att);
  gemm_bt<1><<<dim3(8, 64), 256, 0, stream>>>(att, wpt, b_proj, d_out, 8192, 1024, 1024);
}

// Round 3
// 209.808 us; speedup vs baseline: 2.1217x; 1.1395x over previous
//
#include <hip/hip_runtime.h>
#include <hip/hip_bf16.h>

#define T_SEQ 2048
#define NHEAD 16
#define HDIM  64
#define CDIM  1024

typedef __attribute__((ext_vector_type(8))) short bf16x8;
typedef __attribute__((ext_vector_type(4))) float f32x4;

__device__ __forceinline__ unsigned short f2bf(float f) {
  union { __hip_bfloat16 h; unsigned short u; } c;
  c.h = __float2bfloat16(f);
  return c.u;
}

#define GLD16(g, l) __builtin_amdgcn_global_load_lds( \
  (const __attribute__((address_space(1))) void*)(g), \
  (__attribute__((address_space(3))) void*)(l), 16, 0, 0)

// ---------------- elementwise f32 -> bf16 cast (vectorized) ----------------
__global__ void cvt_bf16(const float* __restrict__ in, unsigned short* __restrict__ out, int n4) {
  const int i = blockIdx.x * 256 + threadIdx.x;
  if (i >= n4) return;
  const float4 v = ((const float4*)in)[i];
  ushort4 o;
  o.x = f2bf(v.x); o.y = f2bf(v.y); o.z = f2bf(v.z); o.w = f2bf(v.w);
  ((ushort4*)out)[i] = o;
}

// ---------------- tiled transpose f32[R][C] -> bf16[C][R] ----------------
__global__ void transpose_cvt(const float* __restrict__ in, unsigned short* __restrict__ out,
                              int R, int C) {
  __shared__ float tile[32][33];
  const int tx = threadIdx.x & 31, ty = threadIdx.x >> 5;
  const int c0 = blockIdx.x * 32, r0 = blockIdx.y * 32;
#pragma unroll
  for (int i = 0; i < 32; i += 8)
    tile[ty + i][tx] = in[(size_t)(r0 + ty + i) * C + c0 + tx];
  __syncthreads();
#pragma unroll
  for (int i = 0; i < 32; i += 8)
    out[(size_t)(c0 + ty + i) * R + r0 + tx] = f2bf(tile[tx][ty + i]);
}

// ---------------- bf16 MFMA GEMM: C[M][N] = A[M][K] * BT[N][K]^T + bias ----------------
template<int OUTF32>
__global__ __launch_bounds__(256, 2)
void gemm_bt(const unsigned short* __restrict__ A, const unsigned short* __restrict__ BT,
             const float* __restrict__ bias, void* __restrict__ outp,
             int M, int N, int K) {
  const int tid = threadIdx.x;
  const int w = tid >> 6, lane = tid & 63;
  const int lg = lane >> 4, l15 = lane & 15;
  const int wr = w >> 1, wc = w & 1;
  const int n0 = blockIdx.x * 128, m0 = blockIdx.y * 128;

  __shared__ unsigned short As[128 * 32];
  __shared__ unsigned short Bs[128 * 32];

  f32x4 acc[4][4] = {};

  for (int k0 = 0; k0 < K; k0 += 32) {
    __syncthreads();
#pragma unroll
    for (int i = 0; i < 2; ++i) {
      const int cb = i * 256 + w * 64;
      const int c  = cb + lane;
      const int row = c >> 2, slot = c & 3;
      GLD16(A  + (size_t)(m0 + row) * K + k0 + slot * 8, (char*)As + cb * 16);
      GLD16(BT + (size_t)(n0 + row) * K + k0 + slot * 8, (char*)Bs + cb * 16);
    }
    __syncthreads();
    bf16x8 af[4], bfr[4];
#pragma unroll
    for (int mt = 0; mt < 4; ++mt)
      af[mt] = *(const bf16x8*)&As[(wr * 64 + mt * 16 + l15) * 32 + lg * 8];
#pragma unroll
    for (int nt = 0; nt < 4; ++nt)
      bfr[nt] = *(const bf16x8*)&Bs[(wc * 64 + nt * 16 + l15) * 32 + lg * 8];
#pragma unroll
    for (int mt = 0; mt < 4; ++mt)
#pragma unroll
      for (int nt = 0; nt < 4; ++nt)
        acc[mt][nt] = __builtin_amdgcn_mfma_f32_16x16x32_bf16(af[mt], bfr[nt], acc[mt][nt], 0, 0, 0);
  }

#pragma unroll
  for (int mt = 0; mt < 4; ++mt) {
#pragma unroll
    for (int nt = 0; nt < 4; ++nt) {
      const int col = n0 + wc * 64 + nt * 16 + l15;
      const float bv = bias[col];
#pragma unroll
      for (int j = 0; j < 4; ++j) {
        const int row = m0 + wr * 64 + mt * 16 + lg * 4 + j;
        const float v = acc[mt][nt][j] + bv;
        if (OUTF32) ((float*)outp)[(size_t)row * N + col] = v;
        else ((unsigned short*)outp)[(size_t)row * N + col] = f2bf(v);
      }
    }
  }
}

// ---------------- causal flash attention v3 ----------------
// 512 threads = 8 waves, each wave owns 16 q rows -> 128 q rows per half.
// Pairing {p, 15-p} over 16 q-tiles -> uniform 34 KV64-tiles/block; grid 512.
// Swapped QK^T (S^T = K*Q^T): softmax in-lane per q-row; defer-max; vector P writes.
#define EXPC 0.18033688f   /* 0.125 * log2(e) */
__global__ __launch_bounds__(512, 4)
void attn_causal3(const unsigned short* __restrict__ qkv, unsigned short* __restrict__ att) {
  const int tid = threadIdx.x;
  const int w = tid >> 6, lane = tid & 63;
  const int lg = lane >> 4, l15 = lane & 15;

  const int fid = blockIdx.x;                   // 0..511
  const int f2 = (fid & 7) * 64 + (fid >> 3);   // XCD-chunked remap (bijective)
  const int pair = f2 & 7, bh = f2 >> 3;
  const int b = bh >> 4, h = bh & 15;

  __shared__ unsigned short Kl[2][2][64][32];   // [buf][kc][kv][el]  64B rows
  __shared__ unsigned short Vt[2][64][64];      // [buf][d][kv^((d>>3)<<3)]
  __shared__ unsigned short Pl[8][16][64];      // [wave][q][kv slot-swizzled]

  const unsigned short* base = qkv + (size_t)b * T_SEQ * 3072;

  auto STAGE_K = [&](int kv0, int buf) {
    const int c = tid;                          // 512 chunks of 16B
    const int kc = c >> 8, kv = (c >> 2) & 63, s2 = c & 3;
    GLD16(base + (size_t)(kv0 + kv) * 3072 + 1024 + h * 64 + kc * 32 + s2 * 8,
          (char*)&Kl[buf][0][0][0] + w * 1024);
  };

  bf16x8 vr;
  const int vkv = tid >> 3, vds = tid & 7;
  auto VLOAD = [&](int kv0) {
    vr = *(const bf16x8*)(base + (size_t)(kv0 + vkv) * 3072 + 2048 + h * 64 + vds * 8);
  };
  auto VWRITE = [&](int buf) {
    const int pos = vkv ^ (vds << 3);
#pragma unroll
    for (int j = 0; j < 8; ++j)
      Vt[buf][vds * 8 + j][pos] = (unsigned short)vr[j];
  };

  for (int half = 0; half < 2; ++half) {
    const int qt = half ? (15 - pair) : pair;
    const int q0 = qt << 7;
    const int ntl = (qt + 1) << 1;              // KV64 tiles
    const int qmin = q0 + w * 16;
    const int qme = qmin + l15;                 // this lane's q row (softmax domain)

    bf16x8 qf[2];
#pragma unroll
    for (int kc = 0; kc < 2; ++kc)
      qf[kc] = *(const bf16x8*)(base + (size_t)qme * 3072 + h * 64 + kc * 32 + lg * 8);

    f32x4 oacc[4] = {};
    float m = -1e30f, l = 0.f;

    STAGE_K(0, 0);
    VLOAD(0);
    VWRITE(0);
    __syncthreads();

    for (int t = 0; t < ntl; ++t) {
      const int cur = t & 1, nxt = cur ^ 1;
      const bool pf = (t + 1) < ntl;
      if (pf) { STAGE_K((t + 1) << 6, nxt); VLOAD((t + 1) << 6); }
      const int kv0 = t << 6;
      const bool skip = kv0 > qmin + 15;        // wave fully masked

      if (!skip) {
        // ---- QK^T swapped: S^T[kv][q] ----
        f32x4 sc[4];
#pragma unroll
        for (int kg = 0; kg < 4; ++kg) {
          f32x4 s = {};
#pragma unroll
          for (int kc = 0; kc < 2; ++kc) {
            bf16x8 kf = *(const bf16x8*)&Kl[cur][kc][kg * 16 + l15][lg * 8];
            s = __builtin_amdgcn_mfma_f32_16x16x32_bf16(kf, qf[kc], s, 0, 0, 0);
          }
          sc[kg] = s;
        }

        // ---- mask (diagonal tiles only) + in-lane max ----
        const bool needmask = (kv0 + 63 > qmin);
        float sv[4][4];
        float mx = -1e30f;
#pragma unroll
        for (int kg = 0; kg < 4; ++kg)
#pragma unroll
          for (int j = 0; j < 4; ++j) {
            float s = sc[kg][j];
            if (needmask && (kv0 + kg * 16 + lg * 4 + j > qme)) s = -1e30f;
            sv[kg][j] = s;
            mx = fmaxf(mx, s);
          }

        // ---- defer-max: rescale only on big max growth ----
        if (__any(mx > m + 55.4f)) {
          float mw = fmaxf(mx, __shfl_xor(mx, 16));
          mw = fmaxf(mw, __shfl_xor(mw, 32));
          const float mnew = fmaxf(m, mw);
          const float alc = exp2f((m - mnew) * EXPC);
          m = mnew;
          l *= alc;
          float alq[4];
#pragma unroll
          for (int j = 0; j < 4; ++j)
            alq[j] = __shfl(alc, (lane & 48) | (lg * 4 + j));
#pragma unroll
          for (int dt = 0; dt < 4; ++dt)
#pragma unroll
            for (int j = 0; j < 4; ++j) oacc[dt][j] *= alq[j];
        }

        // ---- exp + row-sum + vectorized P write ----
        const float mc = m * EXPC;
        float rs = 0.f;
#pragma unroll
        for (int kg = 0; kg < 4; ++kg) {
          ushort4 pw;
          float p0 = exp2f(__fmaf_rn(sv[kg][0], EXPC, -mc));
          float p1 = exp2f(__fmaf_rn(sv[kg][1], EXPC, -mc));
          float p2 = exp2f(__fmaf_rn(sv[kg][2], EXPC, -mc));
          float p3 = exp2f(__fmaf_rn(sv[kg][3], EXPC, -mc));
          rs += (p0 + p1) + (p2 + p3);
          pw.x = f2bf(p0); pw.y = f2bf(p1); pw.z = f2bf(p2); pw.w = f2bf(p3);
          const int slot = (kg * 2 + (lg >> 1)) ^ (l15 & 7);
          *(ushort4*)&Pl[w][l15][slot * 8 + (lg & 1) * 4] = pw;
        }
        rs += __shfl_xor(rs, 16);
        rs += __shfl_xor(rs, 32);
        l += rs;
      }

      // P writes are within-wave producer/consumer: drain LDS, pin order
      asm volatile("s_waitcnt lgkmcnt(0)" ::: "memory");
      __builtin_amdgcn_sched_barrier(0);

      if (!skip) {
        // ---- PV ----
        bf16x8 pa[2];
#pragma unroll
        for (int ks = 0; ks < 2; ++ks)
          pa[ks] = *(const bf16x8*)&Pl[w][l15][((ks * 4 + lg) ^ (l15 & 7)) * 8];
#pragma unroll
        for (int dt = 0; dt < 4; ++dt) {
          f32x4 o = oacc[dt];
          const int d = dt * 16 + l15;
#pragma unroll
          for (int ks = 0; ks < 2; ++ks) {
            bf16x8 vb = *(const bf16x8*)&Vt[cur][d][(ks * 32 + lg * 8) ^ ((d >> 3) << 3)];
            o = __builtin_amdgcn_mfma_f32_16x16x32_bf16(pa[ks], vb, o, 0, 0, 0);
          }
          oacc[dt] = o;
        }
      }

      if (pf) VWRITE(nxt);
      __syncthreads();   // drains vmcnt (K gld_lds) + lgkm (V writes); swap buffers
    }

    // ---- epilogue: broadcast l to O-layout, normalize, store ----
    float lq[4];
#pragma unroll
    for (int j = 0; j < 4; ++j)
      lq[j] = __shfl(l, (lane & 48) | (lg * 4 + j));
#pragma unroll
    for (int dt = 0; dt < 4; ++dt)
#pragma unroll
      for (int j = 0; j < 4; ++j) {
        const int q = qmin + lg * 4 + j;
        att[(size_t)(b * T_SEQ + q) * CDIM + h * HDIM + dt * 16 + l15] =
            f2bf(oacc[dt][j] / lq[j]);
      }
  }
}

// ---------------- launcher ----------------
extern "C" void kernel_launch(void* const* d_in, const int* in_sizes, int n_in,
                              void* d_out, int out_size, void* d_ws, size_t ws_size,
                              hipStream_t stream) {
  const float* x      = (const float*)d_in[0];
  const float* w_attn = (const float*)d_in[1];
  const float* b_attn = (const float*)d_in[2];
  const float* w_proj = (const float*)d_in[3];
  const float* b_proj = (const float*)d_in[4];

  char* ws = (char*)d_ws;
  unsigned short* xb  = (unsigned short*)(ws + 0);           // 8192*1024 bf16
  unsigned short* wat = (unsigned short*)(ws + 16777216);    // 3072*1024 bf16 (w_attn^T)
  unsigned short* wpt = (unsigned short*)(ws + 23068672);    // 1024*1024 bf16 (w_proj^T)
  unsigned short* qkv = (unsigned short*)(ws + 25165824);    // 8192*3072 bf16
  unsigned short* att = (unsigned short*)(ws + 75497472);    // 8192*1024 bf16

  cvt_bf16<<<8192, 256, 0, stream>>>(x, xb, 2097152);
  transpose_cvt<<<dim3(96, 32), 256, 0, stream>>>(w_attn, wat, 1024, 3072);
  transpose_cvt<<<dim3(32, 32), 256, 0, stream>>>(w_proj, wpt, 1024, 1024);
  gemm_bt<0><<<dim3(24, 64), 256, 0, stream>>>(xb, wat, b_attn, (void*)qkv, 8192, 3072, 1024);
  attn_causal3<<<dim3(512), 512, 0, stream>>>(qkv, att);
  gemm_bt<1><<<dim3(8, 64), 256, 0, stream>>>(att, wpt, b_proj, d_out, 8192, 1024, 1024);
}

// Round 4
// 202.909 us; speedup vs baseline: 2.1938x; 1.0340x over previous
//
#include <hip/hip_runtime.h>
#include <hip/hip_bf16.h>

#define T_SEQ 2048
#define NHEAD 16
#define HDIM  64
#define CDIM  1024

typedef __attribute__((ext_vector_type(8))) short bf16x8;
typedef __attribute__((ext_vector_type(4))) short bf16x4;
typedef __attribute__((ext_vector_type(4))) float f32x4;

__device__ __forceinline__ unsigned short f2bf(float f) {
  union { __hip_bfloat16 h; unsigned short u; } c;
  c.h = __float2bfloat16(f);
  return c.u;
}

#define GLD16(g, l) __builtin_amdgcn_global_load_lds( \
  (const __attribute__((address_space(1))) void*)(g), \
  (__attribute__((address_space(3))) void*)(l), 16, 0, 0)

// ---------------- elementwise f32 -> bf16 cast (vectorized) ----------------
__global__ void cvt_bf16(const float* __restrict__ in, unsigned short* __restrict__ out, int n4) {
  const int i = blockIdx.x * 256 + threadIdx.x;
  if (i >= n4) return;
  const float4 v = ((const float4*)in)[i];
  ushort4 o;
  o.x = f2bf(v.x); o.y = f2bf(v.y); o.z = f2bf(v.z); o.w = f2bf(v.w);
  ((ushort4*)out)[i] = o;
}

// ---------------- tiled transpose f32[R][C] -> bf16[C][R] ----------------
__global__ void transpose_cvt(const float* __restrict__ in, unsigned short* __restrict__ out,
                              int R, int C) {
  __shared__ float tile[32][33];
  const int tx = threadIdx.x & 31, ty = threadIdx.x >> 5;
  const int c0 = blockIdx.x * 32, r0 = blockIdx.y * 32;
#pragma unroll
  for (int i = 0; i < 32; i += 8)
    tile[ty + i][tx] = in[(size_t)(r0 + ty + i) * C + c0 + tx];
  __syncthreads();
#pragma unroll
  for (int i = 0; i < 32; i += 8)
    out[(size_t)(c0 + ty + i) * R + r0 + tx] = f2bf(tile[tx][ty + i]);
}

// ---------------- bf16 MFMA GEMM: C[M][N] = A[M][K] * BT[N][K]^T + bias ----------------
template<int OUTF32>
__global__ __launch_bounds__(256, 2)
void gemm_bt(const unsigned short* __restrict__ A, const unsigned short* __restrict__ BT,
             const float* __restrict__ bias, void* __restrict__ outp,
             int M, int N, int K) {
  const int tid = threadIdx.x;
  const int w = tid >> 6, lane = tid & 63;
  const int lg = lane >> 4, l15 = lane & 15;
  const int wr = w >> 1, wc = w & 1;
  const int n0 = blockIdx.x * 128, m0 = blockIdx.y * 128;

  __shared__ unsigned short As[128 * 32];
  __shared__ unsigned short Bs[128 * 32];

  f32x4 acc[4][4] = {};

  for (int k0 = 0; k0 < K; k0 += 32) {
    __syncthreads();
#pragma unroll
    for (int i = 0; i < 2; ++i) {
      const int cb = i * 256 + w * 64;
      const int c  = cb + lane;
      const int row = c >> 2, slot = c & 3;
      GLD16(A  + (size_t)(m0 + row) * K + k0 + slot * 8, (char*)As + cb * 16);
      GLD16(BT + (size_t)(n0 + row) * K + k0 + slot * 8, (char*)Bs + cb * 16);
    }
    __syncthreads();
    bf16x8 af[4], bfr[4];
#pragma unroll
    for (int mt = 0; mt < 4; ++mt)
      af[mt] = *(const bf16x8*)&As[(wr * 64 + mt * 16 + l15) * 32 + lg * 8];
#pragma unroll
    for (int nt = 0; nt < 4; ++nt)
      bfr[nt] = *(const bf16x8*)&Bs[(wc * 64 + nt * 16 + l15) * 32 + lg * 8];
#pragma unroll
    for (int mt = 0; mt < 4; ++mt)
#pragma unroll
      for (int nt = 0; nt < 4; ++nt)
        acc[mt][nt] = __builtin_amdgcn_mfma_f32_16x16x32_bf16(af[mt], bfr[nt], acc[mt][nt], 0, 0, 0);
  }

#pragma unroll
  for (int mt = 0; mt < 4; ++mt) {
#pragma unroll
    for (int nt = 0; nt < 4; ++nt) {
      const int col = n0 + wc * 64 + nt * 16 + l15;
      const float bv = bias[col];
#pragma unroll
      for (int j = 0; j < 4; ++j) {
        const int row = m0 + wr * 64 + mt * 16 + lg * 4 + j;
        const float v = acc[mt][nt][j] + bv;
        if (OUTF32) ((float*)outp)[(size_t)row * N + col] = v;
        else ((unsigned short*)outp)[(size_t)row * N + col] = f2bf(v);
      }
    }
  }
}

// ---------------- causal flash attention v4 ----------------
// v3 + bank-conflict fixes:
//  K: source-preswizzled global_load_lds (slot s holds global slot s^((kv>>1)&3))
//  V: chunk swizzle (c>>3)^(r>>3)^(r&7), staged as 2-row x 4-col b32 packed writes
#define EXPC 0.18033688f   /* 0.125 * log2(e) */
__global__ __launch_bounds__(512, 4)
void attn_causal4(const unsigned short* __restrict__ qkv, unsigned short* __restrict__ att) {
  const int tid = threadIdx.x;
  const int w = tid >> 6, lane = tid & 63;
  const int lg = lane >> 4, l15 = lane & 15;

  const int fid = blockIdx.x;                   // 0..511
  const int f2 = (fid & 7) * 64 + (fid >> 3);   // XCD-chunked remap (bijective)
  const int pair = f2 & 7, bh = f2 >> 3;
  const int b = bh >> 4, h = bh & 15;

  __shared__ unsigned short Kl[2][2][64][32];   // [buf][kc][kv][el], slot-swizzled
  __shared__ unsigned short Vt[2][64][64];      // [buf][d][kv], chunk-swizzled
  __shared__ unsigned short Pl[8][16][64];      // [wave][q][kv slot-swizzled]

  const unsigned short* base = qkv + (size_t)b * T_SEQ * 3072;

  // K stage: LDS chunk c=(kc,kv,spos) fetches global slot spos^((kv>>1)&3).
  auto STAGE_K = [&](int kv0, int buf) {
    const int c = tid;                          // 512 chunks of 16B
    const int kc = c >> 8, kv = (c >> 2) & 63;
    const int s2 = (c & 3) ^ ((kv >> 1) & 3);
    GLD16(base + (size_t)(kv0 + kv) * 3072 + 1024 + h * 64 + kc * 32 + s2 * 8,
          (char*)&Kl[buf][0][0][0] + w * 1024);
  };

  // V stage: thread owns kv rows {2*vkp, 2*vkp+1}, d cols [vd4*4, vd4*4+4)
  bf16x4 vra, vrb;
  const int vkp = tid >> 4, vd4 = tid & 15;
  auto VLOAD = [&](int kv0) {
    const unsigned short* p = base + (size_t)(kv0 + 2 * vkp) * 3072 + 2048 + h * 64 + vd4 * 4;
    vra = *(const bf16x4*)p;
    vrb = *(const bf16x4*)(p + 3072);
  };
  auto VWRITE = [&](int buf) {
    const int ch = vkp >> 2, cl = (vkp & 3) * 2;   // logical chunk, in-chunk pos
#pragma unroll
    for (int j = 0; j < 4; ++j) {
      const int r = vd4 * 4 + j;
      const unsigned int u = (unsigned short)vra[j] |
                             ((unsigned int)(unsigned short)vrb[j] << 16);
      *(unsigned int*)&Vt[buf][r][((ch ^ (r >> 3) ^ (r & 7)) << 3) + cl] = u;
    }
  };

  for (int half = 0; half < 2; ++half) {
    const int qt = half ? (15 - pair) : pair;
    const int q0 = qt << 7;
    const int ntl = (qt + 1) << 1;              // KV64 tiles
    const int qmin = q0 + w * 16;
    const int qme = qmin + l15;                 // this lane's q row (softmax domain)

    bf16x8 qf[2];
#pragma unroll
    for (int kc = 0; kc < 2; ++kc)
      qf[kc] = *(const bf16x8*)(base + (size_t)qme * 3072 + h * 64 + kc * 32 + lg * 8);

    f32x4 oacc[4] = {};
    float m = -1e30f, l = 0.f;

    STAGE_K(0, 0);
    VLOAD(0);
    VWRITE(0);
    __syncthreads();

    for (int t = 0; t < ntl; ++t) {
      const int cur = t & 1, nxt = cur ^ 1;
      const bool pf = (t + 1) < ntl;
      if (pf) { STAGE_K((t + 1) << 6, nxt); VLOAD((t + 1) << 6); }
      const int kv0 = t << 6;
      const bool skip = kv0 > qmin + 15;        // wave fully masked

      if (!skip) {
        // ---- QK^T swapped: S^T[kv][q] ----
        const int ksl = (lg ^ ((l15 >> 1) & 3)) * 8;   // K slot swizzle
        f32x4 sc[4];
#pragma unroll
        for (int kg = 0; kg < 4; ++kg) {
          f32x4 s = {};
#pragma unroll
          for (int kc = 0; kc < 2; ++kc) {
            bf16x8 kf = *(const bf16x8*)&Kl[cur][kc][kg * 16 + l15][ksl];
            s = __builtin_amdgcn_mfma_f32_16x16x32_bf16(kf, qf[kc], s, 0, 0, 0);
          }
          sc[kg] = s;
        }

        // ---- mask (diagonal tiles only) + in-lane max ----
        const bool needmask = (kv0 + 63 > qmin);
        float sv[4][4];
        float mx = -1e30f;
#pragma unroll
        for (int kg = 0; kg < 4; ++kg)
#pragma unroll
          for (int j = 0; j < 4; ++j) {
            float s = sc[kg][j];
            if (needmask && (kv0 + kg * 16 + lg * 4 + j > qme)) s = -1e30f;
            sv[kg][j] = s;
            mx = fmaxf(mx, s);
          }

        // ---- defer-max: rescale only on big max growth ----
        if (__any(mx > m + 55.4f)) {
          float mw = fmaxf(mx, __shfl_xor(mx, 16));
          mw = fmaxf(mw, __shfl_xor(mw, 32));
          const float mnew = fmaxf(m, mw);
          const float alc = exp2f((m - mnew) * EXPC);
          m = mnew;
          l *= alc;
          float alq[4];
#pragma unroll
          for (int j = 0; j < 4; ++j)
            alq[j] = __shfl(alc, (lane & 48) | (lg * 4 + j));
#pragma unroll
          for (int dt = 0; dt < 4; ++dt)
#pragma unroll
            for (int j = 0; j < 4; ++j) oacc[dt][j] *= alq[j];
        }

        // ---- exp + row-sum + vectorized P write ----
        const float mc = m * EXPC;
        float rs = 0.f;
#pragma unroll
        for (int kg = 0; kg < 4; ++kg) {
          ushort4 pw;
          float p0 = exp2f(__fmaf_rn(sv[kg][0], EXPC, -mc));
          float p1 = exp2f(__fmaf_rn(sv[kg][1], EXPC, -mc));
          float p2 = exp2f(__fmaf_rn(sv[kg][2], EXPC, -mc));
          float p3 = exp2f(__fmaf_rn(sv[kg][3], EXPC, -mc));
          rs += (p0 + p1) + (p2 + p3);
          pw.x = f2bf(p0); pw.y = f2bf(p1); pw.z = f2bf(p2); pw.w = f2bf(p3);
          const int slot = (kg * 2 + (lg >> 1)) ^ (l15 & 7);
          *(ushort4*)&Pl[w][l15][slot * 8 + (lg & 1) * 4] = pw;
        }
        rs += __shfl_xor(rs, 16);
        rs += __shfl_xor(rs, 32);
        l += rs;
      }

      // P writes are within-wave producer/consumer: drain LDS, pin order
      asm volatile("s_waitcnt lgkmcnt(0)" ::: "memory");
      __builtin_amdgcn_sched_barrier(0);

      if (!skip) {
        // ---- PV ----
        bf16x8 pa[2];
#pragma unroll
        for (int ks = 0; ks < 2; ++ks)
          pa[ks] = *(const bf16x8*)&Pl[w][l15][((ks * 4 + lg) ^ (l15 & 7)) * 8];
#pragma unroll
        for (int dt = 0; dt < 4; ++dt) {
          f32x4 o = oacc[dt];
          const int d = dt * 16 + l15;
          const int gx = (d >> 3) ^ (d & 7);    // V chunk swizzle
#pragma unroll
          for (int ks = 0; ks < 2; ++ks) {
            bf16x8 vb = *(const bf16x8*)&Vt[cur][d][((ks * 4 + lg) ^ gx) << 3];
            o = __builtin_amdgcn_mfma_f32_16x16x32_bf16(pa[ks], vb, o, 0, 0, 0);
          }
          oacc[dt] = o;
        }
      }

      if (pf) VWRITE(nxt);
      __syncthreads();   // drains vmcnt (K gld_lds) + lgkm (V writes); swap buffers
    }

    // ---- epilogue: broadcast l to O-layout, normalize, store ----
    float lq[4];
#pragma unroll
    for (int j = 0; j < 4; ++j)
      lq[j] = __shfl(l, (lane & 48) | (lg * 4 + j));
#pragma unroll
    for (int dt = 0; dt < 4; ++dt)
#pragma unroll
      for (int j = 0; j < 4; ++j) {
        const int q = qmin + lg * 4 + j;
        att[(size_t)(b * T_SEQ + q) * CDIM + h * HDIM + dt * 16 + l15] =
            f2bf(oacc[dt][j] / lq[j]);
      }
  }
}

// ---------------- launcher ----------------
extern "C" void kernel_launch(void* const* d_in, const int* in_sizes, int n_in,
                              void* d_out, int out_size, void* d_ws, size_t ws_size,
                              hipStream_t stream) {
  const float* x      = (const float*)d_in[0];
  const float* w_attn = (const float*)d_in[1];
  const float* b_attn = (const float*)d_in[2];
  const float* w_proj = (const float*)d_in[3];
  const float* b_proj = (const float*)d_in[4];

  char* ws = (char*)d_ws;
  unsigned short* xb  = (unsigned short*)(ws + 0);           // 8192*1024 bf16
  unsigned short* wat = (unsigned short*)(ws + 16777216);    // 3072*1024 bf16 (w_attn^T)
  unsigned short* wpt = (unsigned short*)(ws + 23068672);    // 1024*1024 bf16 (w_proj^T)
  unsigned short* qkv = (unsigned short*)(ws + 25165824);    // 8192*3072 bf16
  unsigned short* att = (unsigned short*)(ws + 75497472);    // 8192*1024 bf16

  cvt_bf16<<<8192, 256, 0, stream>>>(x, xb, 2097152);
  transpose_cvt<<<dim3(96, 32), 256, 0, stream>>>(w_attn, wat, 1024, 3072);
  transpose_cvt<<<dim3(32, 32), 256, 0, stream>>>(w_proj, wpt, 1024, 1024);
  gemm_bt<0><<<dim3(24, 64), 256, 0, stream>>>(xb, wat, b_attn, (void*)qkv, 8192, 3072, 1024);
  attn_causal4<<<dim3(512), 512, 0, stream>>>(qkv, att);
  gemm_bt<1><<<dim3(8, 64), 256, 0, stream>>>(att, wpt, b_proj, d_out, 8192, 1024, 1024);
}

// Round 5
// 187.605 us; speedup vs baseline: 2.3728x; 1.0816x over previous
//
#include <hip/hip_runtime.h>
#include <hip/hip_bf16.h>

#define T_SEQ 2048
#define NHEAD 16
#define HDIM  64
#define CDIM  1024

typedef __attribute__((ext_vector_type(8))) short bf16x8;
typedef __attribute__((ext_vector_type(4))) short bf16x4;
typedef __attribute__((ext_vector_type(4))) float f32x4;

__device__ __forceinline__ unsigned short f2bf(float f) {
  union { __hip_bfloat16 h; unsigned short u; } c;
  c.h = __float2bfloat16(f);
  return c.u;
}

#define GLD16(g, l) __builtin_amdgcn_global_load_lds( \
  (const __attribute__((address_space(1))) void*)(g), \
  (__attribute__((address_space(3))) void*)(l), 16, 0, 0)

// ---------------- elementwise f32 -> bf16 cast (vectorized) ----------------
__global__ void cvt_bf16(const float* __restrict__ in, unsigned short* __restrict__ out, int n4) {
  const int i = blockIdx.x * 256 + threadIdx.x;
  if (i >= n4) return;
  const float4 v = ((const float4*)in)[i];
  ushort4 o;
  o.x = f2bf(v.x); o.y = f2bf(v.y); o.z = f2bf(v.z); o.w = f2bf(v.w);
  ((ushort4*)out)[i] = o;
}

// ---------------- tiled transpose f32[R][C] -> bf16[C][R] ----------------
__global__ void transpose_cvt(const float* __restrict__ in, unsigned short* __restrict__ out,
                              int R, int C) {
  __shared__ float tile[32][33];
  const int tx = threadIdx.x & 31, ty = threadIdx.x >> 5;
  const int c0 = blockIdx.x * 32, r0 = blockIdx.y * 32;
#pragma unroll
  for (int i = 0; i < 32; i += 8)
    tile[ty + i][tx] = in[(size_t)(r0 + ty + i) * C + c0 + tx];
  __syncthreads();
#pragma unroll
  for (int i = 0; i < 32; i += 8)
    out[(size_t)(c0 + ty + i) * R + r0 + tx] = f2bf(tile[tx][ty + i]);
}

// ---------------- bf16 MFMA GEMM: C[M][N] = A[M][K] * BT[N][K]^T + bias ----------------
template<int OUTF32>
__global__ __launch_bounds__(256, 2)
void gemm_bt(const unsigned short* __restrict__ A, const unsigned short* __restrict__ BT,
             const float* __restrict__ bias, void* __restrict__ outp,
             int M, int N, int K) {
  const int tid = threadIdx.x;
  const int w = tid >> 6, lane = tid & 63;
  const int lg = lane >> 4, l15 = lane & 15;
  const int wr = w >> 1, wc = w & 1;
  const int n0 = blockIdx.x * 128, m0 = blockIdx.y * 128;

  __shared__ unsigned short As[128 * 32];
  __shared__ unsigned short Bs[128 * 32];

  f32x4 acc[4][4] = {};

  for (int k0 = 0; k0 < K; k0 += 32) {
    __syncthreads();
#pragma unroll
    for (int i = 0; i < 2; ++i) {
      const int cb = i * 256 + w * 64;
      const int c  = cb + lane;
      const int row = c >> 2, slot = c & 3;
      GLD16(A  + (size_t)(m0 + row) * K + k0 + slot * 8, (char*)As + cb * 16);
      GLD16(BT + (size_t)(n0 + row) * K + k0 + slot * 8, (char*)Bs + cb * 16);
    }
    __syncthreads();
    bf16x8 af[4], bfr[4];
#pragma unroll
    for (int mt = 0; mt < 4; ++mt)
      af[mt] = *(const bf16x8*)&As[(wr * 64 + mt * 16 + l15) * 32 + lg * 8];
#pragma unroll
    for (int nt = 0; nt < 4; ++nt)
      bfr[nt] = *(const bf16x8*)&Bs[(wc * 64 + nt * 16 + l15) * 32 + lg * 8];
#pragma unroll
    for (int mt = 0; mt < 4; ++mt)
#pragma unroll
      for (int nt = 0; nt < 4; ++nt)
        acc[mt][nt] = __builtin_amdgcn_mfma_f32_16x16x32_bf16(af[mt], bfr[nt], acc[mt][nt], 0, 0, 0);
  }

#pragma unroll
  for (int mt = 0; mt < 4; ++mt) {
#pragma unroll
    for (int nt = 0; nt < 4; ++nt) {
      const int col = n0 + wc * 64 + nt * 16 + l15;
      const float bv = bias[col];
#pragma unroll
      for (int j = 0; j < 4; ++j) {
        const int row = m0 + wr * 64 + mt * 16 + lg * 4 + j;
        const float v = acc[mt][nt][j] + bv;
        if (OUTF32) ((float*)outp)[(size_t)row * N + col] = v;
        else ((unsigned short*)outp)[(size_t)row * N + col] = f2bf(v);
      }
    }
  }
}

// ---------------- causal flash attention v5 ----------------
// K rows bit-permuted in LDS so swapped-QK^T output == PV A-fragment (same lane,
// registers only; no P LDS). Row-sum l via ones-MFMA in O layout. Scalarized mask.
// LDS row 16kg+4lg+j  <->  global kv 32(kg>>1)+4(kg&1)+8lg+j.
#define EXPC 0.18033688f   /* 0.125 * log2(e) */
__global__ __launch_bounds__(512, 4)
void attn_causal5(const unsigned short* __restrict__ qkv, unsigned short* __restrict__ att) {
  const int tid = threadIdx.x;
  const int w = tid >> 6, lane = tid & 63;
  const int lg = lane >> 4, l15 = lane & 15;

  const int fid = blockIdx.x;                   // 0..511
  const int f2 = (fid & 7) * 64 + (fid >> 3);   // XCD-chunked remap (bijective)
  const int pair = f2 & 7, bh = f2 >> 3;
  const int b = bh >> 4, h = bh & 15;

  __shared__ unsigned short Kl[2][2][64][32];   // [buf][kc][ldsrow][el], slot+row permuted
  __shared__ unsigned short Vt[2][64][64];      // [buf][d][kv], chunk-swizzled

  const unsigned short* base = qkv + (size_t)b * T_SEQ * 3072;

  // K stage: LDS row slot holds global kv = bit-permuted(slot); 16B slot swizzle kept.
  auto STAGE_K = [&](int kv0, int buf) {
    const int c = tid;                          // 512 chunks of 16B
    const int kc = c >> 8, slot = (c >> 2) & 63;
    const int s2 = (c & 3) ^ ((slot >> 1) & 3);
    const int v = (slot & 35) | ((slot & 8) << 1) | ((slot & 4) << 1) | ((slot & 16) >> 2);
    GLD16(base + (size_t)(kv0 + v) * 3072 + 1024 + h * 64 + kc * 32 + s2 * 8,
          (char*)&Kl[buf][0][0][0] + w * 1024);
  };

  // V stage: thread owns kv rows {2*vkp, 2*vkp+1}, d cols [vd4*4, vd4*4+4)
  bf16x4 vra, vrb;
  const int vkp = tid >> 4, vd4 = tid & 15;
  auto VLOAD = [&](int kv0) {
    const unsigned short* p = base + (size_t)(kv0 + 2 * vkp) * 3072 + 2048 + h * 64 + vd4 * 4;
    vra = *(const bf16x4*)p;
    vrb = *(const bf16x4*)(p + 3072);
  };
  auto VWRITE = [&](int buf) {
    const int ch = vkp >> 2, cl = (vkp & 3) * 2;
#pragma unroll
    for (int j = 0; j < 4; ++j) {
      const int r = vd4 * 4 + j;
      const unsigned int u = (unsigned short)vra[j] |
                             ((unsigned int)(unsigned short)vrb[j] << 16);
      *(unsigned int*)&Vt[buf][r][((ch ^ (r >> 3) ^ (r & 7)) << 3) + cl] = u;
    }
  };

  bf16x8 ones;
#pragma unroll
  for (int j = 0; j < 8; ++j) ones[j] = (short)0x3F80;   // bf16 1.0

  for (int half = 0; half < 2; ++half) {
    const int qt = half ? (15 - pair) : pair;
    const int q0 = qt << 7;
    const int ntl = (qt + 1) << 1;              // KV64 tiles
    const int qminS = __builtin_amdgcn_readfirstlane(q0 + w * 16);  // wave-uniform SGPR
    const int qme = qminS + l15;                // this lane's q row (softmax domain)

    bf16x8 qf[2];
#pragma unroll
    for (int kc = 0; kc < 2; ++kc)
      qf[kc] = *(const bf16x8*)(base + (size_t)qme * 3072 + h * 64 + kc * 32 + lg * 8);

    f32x4 oacc[4] = {};
    f32x4 lsum = {};
    float m = -1e30f;

    STAGE_K(0, 0);
    VLOAD(0);
    VWRITE(0);
    __syncthreads();

    for (int t = 0; t < ntl; ++t) {
      const int cur = t & 1, nxt = cur ^ 1;
      const bool pf = (t + 1) < ntl;
      if (pf) { STAGE_K((t + 1) << 6, nxt); VLOAD((t + 1) << 6); }
      const int kv0 = t << 6;

      if (kv0 <= qminS + 15) {                  // wave has unmasked work (scalar branch)
        // ---- QK^T swapped: S^T in permuted-kv layout ----
        const int ksl = (lg ^ ((l15 >> 1) & 3)) * 8;
        f32x4 sc[4];
        __builtin_amdgcn_s_setprio(1);
#pragma unroll
        for (int kg = 0; kg < 4; ++kg) {
          f32x4 s = {};
#pragma unroll
          for (int kc = 0; kc < 2; ++kc) {
            bf16x8 kf = *(const bf16x8*)&Kl[cur][kc][kg * 16 + l15][ksl];
            s = __builtin_amdgcn_mfma_f32_16x16x32_bf16(kf, qf[kc], s, 0, 0, 0);
          }
          sc[kg] = s;
        }
        __builtin_amdgcn_s_setprio(0);

        // ---- mask (diagonal tiles only, scalar-guarded) ----
        float sv[4][4];
        if (kv0 + 63 > qminS) {
#pragma unroll
          for (int kg = 0; kg < 4; ++kg) {
            const int colb = kv0 + ((kg >> 1) << 5) + ((kg & 1) << 2) + lg * 8;
#pragma unroll
            for (int j = 0; j < 4; ++j)
              sv[kg][j] = (colb + j <= qme) ? sc[kg][j] : -1e30f;
          }
        } else {
#pragma unroll
          for (int kg = 0; kg < 4; ++kg)
#pragma unroll
            for (int j = 0; j < 4; ++j) sv[kg][j] = sc[kg][j];
        }

        // ---- tree max ----
        float mx = -1e30f;
#pragma unroll
        for (int kg = 0; kg < 4; ++kg) {
          const float a = fmaxf(sv[kg][0], sv[kg][1]);
          const float c2 = fmaxf(sv[kg][2], sv[kg][3]);
          mx = fmaxf(mx, fmaxf(a, c2));
        }

        // ---- defer-max rescale (rare) ----
        if (__any(mx > m + 55.4f)) {
          float mw = fmaxf(mx, __shfl_xor(mx, 16));
          mw = fmaxf(mw, __shfl_xor(mw, 32));
          const float mnew = fmaxf(m, mw);
          const float alc = exp2f((m - mnew) * EXPC);
          m = mnew;
          float alq[4];
#pragma unroll
          for (int j = 0; j < 4; ++j)
            alq[j] = __shfl(alc, (lane & 48) | (lg * 4 + j));
#pragma unroll
          for (int j = 0; j < 4; ++j) {
            lsum[j] *= alq[j];
#pragma unroll
            for (int dt = 0; dt < 4; ++dt) oacc[dt][j] *= alq[j];
          }
        }

        // ---- exp -> PV A-fragments (registers, same lane) ----
        const float mc = m * EXPC;
        bf16x8 pa[2];
#pragma unroll
        for (int kg = 0; kg < 4; ++kg) {
          const int ks = kg >> 1, off = (kg & 1) * 4;
#pragma unroll
          for (int j = 0; j < 4; ++j) {
            const float p = exp2f(__fmaf_rn(sv[kg][j], EXPC, -mc));
            pa[ks][off + j] = (short)f2bf(p);
          }
        }

        // ---- l via ones-MFMA + PV ----
        __builtin_amdgcn_s_setprio(1);
        lsum = __builtin_amdgcn_mfma_f32_16x16x32_bf16(pa[0], ones, lsum, 0, 0, 0);
        lsum = __builtin_amdgcn_mfma_f32_16x16x32_bf16(pa[1], ones, lsum, 0, 0, 0);
#pragma unroll
        for (int dt = 0; dt < 4; ++dt) {
          f32x4 o = oacc[dt];
          const int d = dt * 16 + l15;
          const int gx = (d >> 3) ^ (d & 7);    // V chunk swizzle
#pragma unroll
          for (int ks = 0; ks < 2; ++ks) {
            bf16x8 vb = *(const bf16x8*)&Vt[cur][d][((ks * 4 + lg) ^ gx) << 3];
            o = __builtin_amdgcn_mfma_f32_16x16x32_bf16(pa[ks], vb, o, 0, 0, 0);
          }
          oacc[dt] = o;
        }
        __builtin_amdgcn_s_setprio(0);
      }

      if (pf) VWRITE(nxt);
      __syncthreads();   // drains vmcnt (K gld_lds) + lgkm (V writes); swap buffers
    }

    // ---- epilogue: normalize by lsum (already in O layout), store ----
#pragma unroll
    for (int dt = 0; dt < 4; ++dt)
#pragma unroll
      for (int j = 0; j < 4; ++j) {
        const int q = qminS + lg * 4 + j;
        att[(size_t)(b * T_SEQ + q) * CDIM + h * HDIM + dt * 16 + l15] =
            f2bf(oacc[dt][j] / lsum[j]);
      }
  }
}

// ---------------- launcher ----------------
extern "C" void kernel_launch(void* const* d_in, const int* in_sizes, int n_in,
                              void* d_out, int out_size, void* d_ws, size_t ws_size,
                              hipStream_t stream) {
  const float* x      = (const float*)d_in[0];
  const float* w_attn = (const float*)d_in[1];
  const float* b_attn = (const float*)d_in[2];
  const float* w_proj = (const float*)d_in[3];
  const float* b_proj = (const float*)d_in[4];

  char* ws = (char*)d_ws;
  unsigned short* xb  = (unsigned short*)(ws + 0);           // 8192*1024 bf16
  unsigned short* wat = (unsigned short*)(ws + 16777216);    // 3072*1024 bf16 (w_attn^T)
  unsigned short* wpt = (unsigned short*)(ws + 23068672);    // 1024*1024 bf16 (w_proj^T)
  unsigned short* qkv = (unsigned short*)(ws + 25165824);    // 8192*3072 bf16
  unsigned short* att = (unsigned short*)(ws + 75497472);    // 8192*1024 bf16

  cvt_bf16<<<8192, 256, 0, stream>>>(x, xb, 2097152);
  transpose_cvt<<<dim3(96, 32), 256, 0, stream>>>(w_attn, wat, 1024, 3072);
  transpose_cvt<<<dim3(32, 32), 256, 0, stream>>>(w_proj, wpt, 1024, 1024);
  gemm_bt<0><<<dim3(24, 64), 256, 0, stream>>>(xb, wat, b_attn, (void*)qkv, 8192, 3072, 1024);
  attn_causal5<<<dim3(512), 512, 0, stream>>>(qkv, att);
  gemm_bt<1><<<dim3(8, 64), 256, 0, stream>>>(att, wpt, b_proj, d_out, 8192, 1024, 1024);
}